// Round 9
// baseline (154.571 us; speedup 1.0000x reference)
//
#include <hip/hip_runtime.h>
#include <hip/hip_bf16.h>

#define B_   64
#define S_   2048
#define H_   256
#define H3_  768
#define K_   512            // 2H (static+dynamic)
#define MT   64             // M tile rows
#define TPB  8              // tiles per persistent block
#define NB   256            // persistent blocks (1/CU)
#define RSTR 1040           // LDS row stride bytes (65x16B): conflict-free, imm-foldable
#define BUFB (MT * RSTR)    // 66560 B per buffer

typedef __attribute__((ext_vector_type(8))) short  bf16x8;
typedef __attribute__((ext_vector_type(4))) float  f32x4;

__device__ __forceinline__ uint pkbf2(float a, float b) {
    float2 f = make_float2(a, b);
    __hip_bfloat162 h = __float22bfloat162_rn(f);   // v_cvt_pk_bf16_f32
    return *reinterpret_cast<uint*>(&h);
}

// ---------------- kernel 1: pack W[:, 0:512] to bf16 in FRAGMENT order.
// Layout: [ot(48)][ks(16)][lane(64)][j(8)]
//   o = ot*16 + (lane&15), k = ks*32 + (lane>>4)*8 + j
__global__ void pack_w(const float* __restrict__ W, short* __restrict__ wpk) {
    int t = blockIdx.x * 256 + threadIdx.x;       // over 48*16*64
    if (t >= 48 * 16 * 64) return;
    int lane = t & 63;
    int ks   = (t >> 6) & 15;
    int ot   = t >> 10;
    int o  = ot * 16 + (lane & 15);
    int kb = ks * 32 + (lane >> 4) * 8;
    const float* src = W + (size_t)o * H3_ + kb;
    float4 a = ((const float4*)src)[0];
    float4 b = ((const float4*)src)[1];
    uint4 pk;
    pk.x = pkbf2(a.x, a.y);
    pk.y = pkbf2(a.z, a.w);
    pk.z = pkbf2(b.x, b.y);
    pk.w = pkbf2(b.z, b.w);
    *(uint4*)(wpk + (size_t)t * 8) = pk;
}

// ---------------- kernel 2: bias[b,o] = sum_k W[o,512+k]*dec[b,k]; block 192: vsum
__global__ void bias_k(const float* __restrict__ W, const float* __restrict__ dec,
                       const float* __restrict__ v, float* __restrict__ bias,
                       float* __restrict__ vsum) {
    if (blockIdx.x == 192) {                      // reduce sum(v) with one wave
        if (threadIdx.x < 64) {
            float s = 0.f;
#pragma unroll
            for (int i = 0; i < 12; ++i) s += v[threadIdx.x + i * 64];
#pragma unroll
            for (int off = 32; off >= 1; off >>= 1) s += __shfl_xor(s, off);
            if (threadIdx.x == 0) vsum[0] = s;
        }
        return;
    }
    int idx = blockIdx.x * 256 + threadIdx.x;     // over 64*768
    int b = idx / H3_;
    int o = idx - b * H3_;
    const float4* wr = (const float4*)(W + (size_t)o * H3_ + 2 * H_);
    const float4* dv = (const float4*)(dec + (size_t)b * H_);
    float s = 0.f;
#pragma unroll 8
    for (int k = 0; k < H_ / 4; ++k) {
        float4 a = wr[k], d = dv[k];
        s += a.x * d.x + a.y * d.y + a.z * d.z + a.w * d.w;
    }
    bias[idx] = s;
}

// ---------------- kernel 3: fused score GEMM, persistent + double-buffered.
// 8 waves; wave covers cols wave*96 + p*48 + ni*16 (p=0..1, ni=0..2).
// Stage tile t+1 in 3 register-lean chunks overlapped with compute of t.
// scores[pos] = vsum + sum_o (-2 v[o]) * rcp(exp2(C1*h[pos,o]) + 1)
__global__ __launch_bounds__(512, 2)
void score_k(const float* __restrict__ stat, const float* __restrict__ dyn,
             const short* __restrict__ wpk, const float* __restrict__ bias,
             const float* __restrict__ v, const float* __restrict__ vsum,
             float* __restrict__ scores) {
    __shared__ char  aT[2 * BUFB];           // 130 KB double buffer
    __shared__ float sred[2][8][MT];         // 4 KB, parity-alternated

    const int tid  = threadIdx.x;
    const int wave = tid >> 6;
    const int lane = tid & 63;
    const int lr   = lane & 15;
    const int lg   = lane >> 4;

    const int row0 = blockIdx.x * (TPB * MT);    // block's first global row
    const int bidx = row0 >> 11;                 // never crosses b (512 | 2048)

    const float vs = vsum[0];

    // hoisted per-block epilogue constants
    float bvA[2][3], vvA[2][3];
#pragma unroll
    for (int p = 0; p < 2; ++p)
#pragma unroll
        for (int ni = 0; ni < 3; ++ni) {
            int o = wave * 96 + p * 48 + ni * 16 + lr;
            bvA[p][ni] = bias[bidx * H3_ + o];
            vvA[p][ni] = -2.0f * v[o];
        }

    // staging: unit u (0..7): row = u*8 + wave, k = lane*8 (stat k<256, dyn else)
    const int kcol = lane * 8;
    const float* srcbase = (kcol < 256) ? (stat + kcol) : (dyn + (kcol - 256));

    float4 f0[3], f1[3];
    auto loadu = [&](int u0, int n, int grow0) {
#pragma unroll
        for (int i = 0; i < n; ++i) {
            int row = (u0 + i) * 8 + wave;
            const float4* p = (const float4*)(srcbase + (size_t)(grow0 + row) * H_);
            f0[i] = p[0];
            f1[i] = p[1];
        }
    };
    auto writeu = [&](int u0, int n, int bufoff) {
#pragma unroll
        for (int i = 0; i < n; ++i) {
            int row = (u0 + i) * 8 + wave;
            uint4 pk;
            pk.x = pkbf2(f0[i].x, f0[i].y);
            pk.y = pkbf2(f0[i].z, f0[i].w);
            pk.z = pkbf2(f1[i].x, f1[i].y);
            pk.w = pkbf2(f1[i].z, f1[i].w);
            *(uint4*)(aT + bufoff + row * RSTR + lane * 16) = pk;
        }
    };

    // prologue: stage tile 0 into buffer 0
    loadu(0, 3, row0); writeu(0, 3, 0);
    loadu(3, 3, row0); writeu(3, 3, 0);
    loadu(6, 2, row0); writeu(6, 2, 0);
    __syncthreads();

    const char* abase0 = aT + lr * RSTR + lg * 16;
    const float C1 = 2.8853900817779268f;    // 2*log2(e)

#pragma unroll 1
    for (int t = 0; t < TPB; ++t) {
        const int pos0 = row0 + t * MT;
        const int cbuf = (t & 1) * BUFB;
        const int nbuf = ((t & 1) ^ 1) * BUFB;
        const int grown = pos0 + MT;
        const bool pre = (t < TPB - 1);
        const char* abase = abase0 + cbuf;

        float sacc[4][4];
#pragma unroll
        for (int mi = 0; mi < 4; ++mi)
#pragma unroll
            for (int j = 0; j < 4; ++j) sacc[mi][j] = 0.f;

        if (pre) loadu(0, 3, grown);         // chunk 0 in flight under pass 0

        // ---------------- pass 0
        {
            f32x4 acc[4][3];
#pragma unroll
            for (int mi = 0; mi < 4; ++mi)
#pragma unroll
                for (int ni = 0; ni < 3; ++ni) {
                    f32x4 a = {bvA[0][ni], bvA[0][ni], bvA[0][ni], bvA[0][ni]};
                    acc[mi][ni] = a;
                }
            // ot = wave*6 ; one ot block = 16*64*8 = 8192 shorts
            const short* wp0 = wpk + (size_t)(wave * 6) * 8192 + lane * 8;
#pragma unroll 4
            for (int ks = 0; ks < 16; ++ks) {
                bf16x8 bfr[3];
#pragma unroll
                for (int ni = 0; ni < 3; ++ni)
                    bfr[ni] = *(const bf16x8*)(wp0 + ni * 8192 + ks * 512);
                bf16x8 afr[4];
#pragma unroll
                for (int mi = 0; mi < 4; ++mi)
                    afr[mi] = *(const bf16x8*)(abase + mi * (16 * RSTR) + ks * 64);
#pragma unroll
                for (int mi = 0; mi < 4; ++mi)
#pragma unroll
                    for (int ni = 0; ni < 3; ++ni)
                        acc[mi][ni] = __builtin_amdgcn_mfma_f32_16x16x32_bf16(
                            afr[mi], bfr[ni], acc[mi][ni], 0, 0, 0);
            }
#pragma unroll
            for (int ni = 0; ni < 3; ++ni)
#pragma unroll
                for (int mi = 0; mi < 4; ++mi)
#pragma unroll
                    for (int j = 0; j < 4; ++j) {
                        float e = __builtin_amdgcn_exp2f(acc[mi][ni][j] * C1);
                        float r = __builtin_amdgcn_rcpf(e + 1.0f);
                        sacc[mi][j] = fmaf(vvA[0][ni], r, sacc[mi][j]);
                    }
        }

        if (pre) { writeu(0, 3, nbuf); loadu(3, 3, grown); }

        // ---------------- pass 1 (split ks halves around staging milestone)
        {
            f32x4 acc[4][3];
#pragma unroll
            for (int mi = 0; mi < 4; ++mi)
#pragma unroll
                for (int ni = 0; ni < 3; ++ni) {
                    f32x4 a = {bvA[1][ni], bvA[1][ni], bvA[1][ni], bvA[1][ni]};
                    acc[mi][ni] = a;
                }
            // ot = wave*6 + 3
            const short* wp1 = wpk + (size_t)(wave * 6 + 3) * 8192 + lane * 8;
#pragma unroll 4
            for (int ks = 0; ks < 8; ++ks) {
                bf16x8 bfr[3];
#pragma unroll
                for (int ni = 0; ni < 3; ++ni)
                    bfr[ni] = *(const bf16x8*)(wp1 + ni * 8192 + ks * 512);
                bf16x8 afr[4];
#pragma unroll
                for (int mi = 0; mi < 4; ++mi)
                    afr[mi] = *(const bf16x8*)(abase + mi * (16 * RSTR) + ks * 64);
#pragma unroll
                for (int mi = 0; mi < 4; ++mi)
#pragma unroll
                    for (int ni = 0; ni < 3; ++ni)
                        acc[mi][ni] = __builtin_amdgcn_mfma_f32_16x16x32_bf16(
                            afr[mi], bfr[ni], acc[mi][ni], 0, 0, 0);
            }

            if (pre) { writeu(3, 3, nbuf); loadu(6, 2, grown); }

#pragma unroll 4
            for (int ks = 8; ks < 16; ++ks) {
                bf16x8 bfr[3];
#pragma unroll
                for (int ni = 0; ni < 3; ++ni)
                    bfr[ni] = *(const bf16x8*)(wp1 + ni * 8192 + ks * 512);
                bf16x8 afr[4];
#pragma unroll
                for (int mi = 0; mi < 4; ++mi)
                    afr[mi] = *(const bf16x8*)(abase + mi * (16 * RSTR) + ks * 64);
#pragma unroll
                for (int mi = 0; mi < 4; ++mi)
#pragma unroll
                    for (int ni = 0; ni < 3; ++ni)
                        acc[mi][ni] = __builtin_amdgcn_mfma_f32_16x16x32_bf16(
                            afr[mi], bfr[ni], acc[mi][ni], 0, 0, 0);
            }

            if (pre) writeu(6, 2, nbuf);

#pragma unroll
            for (int ni = 0; ni < 3; ++ni)
#pragma unroll
                for (int mi = 0; mi < 4; ++mi)
#pragma unroll
                    for (int j = 0; j < 4; ++j) {
                        float e = __builtin_amdgcn_exp2f(acc[mi][ni][j] * C1);
                        float r = __builtin_amdgcn_rcpf(e + 1.0f);
                        sacc[mi][j] = fmaf(vvA[1][ni], r, sacc[mi][j]);
                    }
        }

        // reduce over 16 column-lanes; rows live at mi*16 + lg*4 + j
#pragma unroll
        for (int mi = 0; mi < 4; ++mi)
#pragma unroll
            for (int j = 0; j < 4; ++j) {
                float x = sacc[mi][j];
                x += __shfl_xor(x, 1);
                x += __shfl_xor(x, 2);
                x += __shfl_xor(x, 4);
                x += __shfl_xor(x, 8);
                sacc[mi][j] = x;
            }
        if (lr == 0) {
#pragma unroll
            for (int mi = 0; mi < 4; ++mi)
#pragma unroll
                for (int j = 0; j < 4; ++j)
                    sred[t & 1][wave][mi * 16 + lg * 4 + j] = sacc[mi][j];
        }
        __syncthreads();   // sred(t) visible AND buf(t+1) fully staged
        if (tid < MT) {
            float s = vs;
#pragma unroll
            for (int w = 0; w < 8; ++w) s += sred[t & 1][w][tid];
            scores[pos0 + tid] = s;
        }
    }
}

// ---------------- kernel 4: softmax over S=2048 per b, in place on d_out
__global__ void softmax_k(float* __restrict__ out) {
    const int b = blockIdx.x;
    float* row = out + (size_t)b * S_;
    const int tid  = threadIdx.x;          // 256
    const int wave = tid >> 6;
    const int lane = tid & 63;

    float vals[8];
    float m = -1e30f;
#pragma unroll
    for (int i = 0; i < 8; ++i) {
        vals[i] = row[tid + i * 256];
        m = fmaxf(m, vals[i]);
    }
#pragma unroll
    for (int off = 32; off >= 1; off >>= 1) m = fmaxf(m, __shfl_xor(m, off));
    __shared__ float redm[4];
    __shared__ float reds[4];
    if (lane == 0) redm[wave] = m;
    __syncthreads();
    m = fmaxf(fmaxf(redm[0], redm[1]), fmaxf(redm[2], redm[3]));

    float s = 0.f;
#pragma unroll
    for (int i = 0; i < 8; ++i) {
        vals[i] = __expf(vals[i] - m);
        s += vals[i];
    }
#pragma unroll
    for (int off = 32; off >= 1; off >>= 1) s += __shfl_xor(s, off);
    if (lane == 0) reds[wave] = s;
    __syncthreads();
    s = reds[0] + reds[1] + reds[2] + reds[3];
    float inv = 1.0f / s;
#pragma unroll
    for (int i = 0; i < 8; ++i) row[tid + i * 256] = vals[i] * inv;
}

extern "C" void kernel_launch(void* const* d_in, const int* in_sizes, int n_in,
                              void* d_out, int out_size, void* d_ws, size_t ws_size,
                              hipStream_t stream) {
    const float* stat = (const float*)d_in[0];   // [64,2048,256]
    const float* dyn  = (const float*)d_in[1];   // [64,2048,256]
    const float* dec  = (const float*)d_in[2];   // [64,256]
    const float* v    = (const float*)d_in[3];   // [1,768]
    const float* W    = (const float*)d_in[4];   // [768,768]
    float* out = (float*)d_out;                  // [64,2048]

    short* wpk  = (short*)d_ws;                                 // 786432 B
    float* bias = (float*)((char*)d_ws + (size_t)H3_ * K_ * 2); // 196608 B
    float* vsum = bias + B_ * H3_;                              // 4 B

    pack_w <<<(48 * 16 * 64 + 255) / 256, 256, 0, stream>>>(W, wpk);
    bias_k <<<193, 256, 0, stream>>>(W, dec, v, bias, vsum);
    score_k<<<NB, 512, 0, stream>>>(stat, dyn, wpk, bias, v, vsum, out);
    softmax_k<<<B_, 256, 0, stream>>>(out);
}

// Round 10
// 136.293 us; speedup vs baseline: 1.1341x; 1.1341x over previous
//
#include <hip/hip_runtime.h>
#include <hip/hip_bf16.h>

#define B_   64
#define S_   2048
#define H_   256
#define H3_  768
#define K_   512            // 2H (static+dynamic)
#define MT   64             // M tile (positions per workgroup)
#define RSTR 1040           // LDS row stride in bytes (65 x 16B): 2-way banks, imm-foldable

typedef __attribute__((ext_vector_type(8))) short  bf16x8;
typedef __attribute__((ext_vector_type(4))) float  f32x4;

__device__ __forceinline__ uint pkbf2(float a, float b) {
    float2 f = make_float2(a, b);
    __hip_bfloat162 h = __float22bfloat162_rn(f);   // v_cvt_pk_bf16_f32
    return *reinterpret_cast<uint*>(&h);
}

// ---------------- kernel 1: pack W[:, 0:512] to bf16 in FRAGMENT order.
// Layout: [ot(48)][ks(16)][lane(64)][j(8)]
//   o = ot*16 + (lane&15), k = ks*32 + (lane>>4)*8 + j
__global__ void pack_w(const float* __restrict__ W, short* __restrict__ wpk) {
    int t = blockIdx.x * 256 + threadIdx.x;       // over 48*16*64
    if (t >= 48 * 16 * 64) return;
    int lane = t & 63;
    int ks   = (t >> 6) & 15;
    int ot   = t >> 10;
    int o  = ot * 16 + (lane & 15);
    int kb = ks * 32 + (lane >> 4) * 8;
    const float* src = W + (size_t)o * H3_ + kb;
    float4 a = ((const float4*)src)[0];
    float4 b = ((const float4*)src)[1];
    uint4 pk;
    pk.x = pkbf2(a.x, a.y);
    pk.y = pkbf2(a.z, a.w);
    pk.z = pkbf2(b.x, b.y);
    pk.w = pkbf2(b.z, b.w);
    *(uint4*)(wpk + (size_t)t * 8) = pk;
}

// ---------------- kernel 2: bias[b,o] = sum_k W[o,512+k]*dec[b,k]; block 192: vsum
__global__ void bias_k(const float* __restrict__ W, const float* __restrict__ dec,
                       const float* __restrict__ v, float* __restrict__ bias,
                       float* __restrict__ vsum) {
    if (blockIdx.x == 192) {                      // reduce sum(v) with one wave
        if (threadIdx.x < 64) {
            float s = 0.f;
#pragma unroll
            for (int i = 0; i < 12; ++i) s += v[threadIdx.x + i * 64];
#pragma unroll
            for (int off = 32; off >= 1; off >>= 1) s += __shfl_xor(s, off);
            if (threadIdx.x == 0) vsum[0] = s;
        }
        return;
    }
    int idx = blockIdx.x * 256 + threadIdx.x;     // over 64*768
    int b = idx / H3_;
    int o = idx - b * H3_;
    const float4* wr = (const float4*)(W + (size_t)o * H3_ + 2 * H_);
    const float4* dv = (const float4*)(dec + (size_t)b * H_);
    float s = 0.f;
#pragma unroll 8
    for (int k = 0; k < H_ / 4; ++k) {
        float4 a = wr[k], d = dv[k];
        s += a.x * d.x + a.y * d.y + a.z * d.z + a.w * d.w;
    }
    bias[idx] = s;
}

// ---------------- kernel 3: fused score GEMM (R7 skeleton + B software pipeline)
// scores[pos] = vsum + sum_o (-2 v[o]) * rcp(exp2(C1*h[pos,o]) + 1)
//   where h = X·W^T + bias  (tanh identity), C1 = 2*log2(e)
__global__ __launch_bounds__(256, 2)
void score_k(const float* __restrict__ stat, const float* __restrict__ dyn,
             const short* __restrict__ wpk, const float* __restrict__ bias,
             const float* __restrict__ v, const float* __restrict__ vsum,
             float* __restrict__ scores) {
    __shared__ char  aT[MT * RSTR];          // 65 KB, pad-1040 layout
    __shared__ float sred[4][MT];            // 1 KB

    const int tid  = threadIdx.x;
    const int pos0 = blockIdx.x * MT;
    const int bidx = pos0 >> 11;             // /2048 ; tile never crosses b

    const int wave = tid >> 6;
    const int lane = tid & 63;
    const int lr = lane & 15;                // A: row-in-16 ; B/C: col-in-16
    const int lg = lane >> 4;                // k-group (8 elems each)

    const short* wbase = wpk + (size_t)lane * 8;   // + ot*8192 + ks*512

    // preload pass-0 ks-0 B fragments: latency hides under the staging phase
    bf16x8 bcur[4];
#pragma unroll
    for (int ni = 0; ni < 4; ++ni)
        bcur[ni] = *(const bf16x8*)(wbase + (size_t)(wave * 4 + ni) * 8192);

    // ---- stage A: 64 rows x 512 k; 8 floats/unit (2x float4 -> 16B ds_write)
#pragma unroll
    for (int bat = 0; bat < 2; ++bat) {
        float4 f0[8], f1[8];
#pragma unroll
        for (int u = 0; u < 8; ++u) {
            int lin = (bat * 8 + u) * 256 + tid;
            int row = lin >> 6;              // 64 units per row
            int k   = (lin & 63) * 8;
            const float* src = (k < 256)
                ? (stat + (size_t)(pos0 + row) * H_ + k)
                : (dyn  + (size_t)(pos0 + row) * H_ + (k - 256));
            f0[u] = ((const float4*)src)[0];
            f1[u] = ((const float4*)src)[1];
        }
#pragma unroll
        for (int u = 0; u < 8; ++u) {
            int lin = (bat * 8 + u) * 256 + tid;
            int row = lin >> 6;
            int ux  = lin & 63;
            uint4 pk;
            pk.x = pkbf2(f0[u].x, f0[u].y);
            pk.y = pkbf2(f0[u].z, f0[u].w);
            pk.z = pkbf2(f1[u].x, f1[u].y);
            pk.w = pkbf2(f1[u].z, f1[u].w);
            *(uint4*)(aT + row * RSTR + ux * 16) = pk;
        }
    }
    __syncthreads();

    // single base address for A-fragment reads (imm offsets cover mi, ks window)
    const char* abase = aT + lr * RSTR + lg * 16;

    float sacc[4][4];
#pragma unroll
    for (int mi = 0; mi < 4; ++mi)
#pragma unroll
        for (int j = 0; j < 4; ++j) sacc[mi][j] = 0.f;

    const float C1 = 2.8853900817779268f;    // 2*log2(e)

    // 3 passes x (4 waves x 64 cols) = 768 cols
#pragma unroll 1
    for (int pass = 0; pass < 3; ++pass) {
        const int obase = pass * 256 + wave * 64;      // this wave's 64 cols

        float bv[4], vv2[4];
#pragma unroll
        for (int ni = 0; ni < 4; ++ni) {
            int o = obase + ni * 16 + lr;
            bv[ni]  = bias[bidx * H3_ + o];
            vv2[ni] = -2.0f * v[o];
        }

        f32x4 acc[4][4];                               // [mi][ni], init = bias
#pragma unroll
        for (int mi = 0; mi < 4; ++mi)
#pragma unroll
            for (int ni = 0; ni < 4; ++ni) {
                f32x4 a = {bv[ni], bv[ni], bv[ni], bv[ni]};
                acc[mi][ni] = a;
            }

        const short* wp0 = wbase + (size_t)(pass * 16 + wave * 4) * 8192;

#pragma unroll 4
        for (int ks = 0; ks < 16; ++ks) {
            // 1-step lookahead for B: consumption is ~600 cyc after issue
            const int ksn = (ks + 1) & 15;             // wrap: dummy reload, overwritten below
            bf16x8 bnx[4];
#pragma unroll
            for (int ni = 0; ni < 4; ++ni)
                bnx[ni] = *(const bf16x8*)(wp0 + ni * 8192 + ksn * 512);
            bf16x8 afr[4];
#pragma unroll
            for (int mi = 0; mi < 4; ++mi)
                afr[mi] = *(const bf16x8*)(abase + mi * 16 * RSTR + ks * 64);
            __builtin_amdgcn_s_setprio(1);
#pragma unroll
            for (int mi = 0; mi < 4; ++mi)
#pragma unroll
                for (int ni = 0; ni < 4; ++ni)
                    acc[mi][ni] = __builtin_amdgcn_mfma_f32_16x16x32_bf16(
                        afr[mi], bcur[ni], acc[mi][ni], 0, 0, 0);
            __builtin_amdgcn_s_setprio(0);
#pragma unroll
            for (int ni = 0; ni < 4; ++ni) bcur[ni] = bnx[ni];
        }

        // preload next pass's ks-0 B fragments; epilogue covers the latency
        if (pass < 2) {
            const short* wpn = wbase + (size_t)((pass + 1) * 16 + wave * 4) * 8192;
#pragma unroll
            for (int ni = 0; ni < 4; ++ni)
                bcur[ni] = *(const bf16x8*)(wpn + ni * 8192);
        }

        // epilogue: sacc += (-2 v) * rcp(exp2(C1*h)+1)
#pragma unroll
        for (int ni = 0; ni < 4; ++ni)
#pragma unroll
            for (int mi = 0; mi < 4; ++mi)
#pragma unroll
                for (int j = 0; j < 4; ++j) {
                    float e = __builtin_amdgcn_exp2f(acc[mi][ni][j] * C1);
                    float r = __builtin_amdgcn_rcpf(e + 1.0f);
                    sacc[mi][j] = fmaf(vv2[ni], r, sacc[mi][j]);
                }
    }

    // reduce over the 16 column-lanes (lr); rows live at mi*16 + lg*4 + j
#pragma unroll
    for (int mi = 0; mi < 4; ++mi)
#pragma unroll
        for (int j = 0; j < 4; ++j) {
            float x = sacc[mi][j];
            x += __shfl_xor(x, 1);
            x += __shfl_xor(x, 2);
            x += __shfl_xor(x, 4);
            x += __shfl_xor(x, 8);
            sacc[mi][j] = x;
        }
    if (lr == 0) {
#pragma unroll
        for (int mi = 0; mi < 4; ++mi)
#pragma unroll
            for (int j = 0; j < 4; ++j)
                sred[wave][mi * 16 + lg * 4 + j] = sacc[mi][j];
    }
    __syncthreads();
    if (tid < MT) {
        float s = vsum[0] + sred[0][tid] + sred[1][tid] + sred[2][tid] + sred[3][tid];
        scores[pos0 + tid] = s;
    }
}

// ---------------- kernel 4: softmax over S=2048 per b, in place on d_out
__global__ void softmax_k(float* __restrict__ out) {
    const int b = blockIdx.x;
    float* row = out + (size_t)b * S_;
    const int tid  = threadIdx.x;          // 256
    const int wave = tid >> 6;
    const int lane = tid & 63;

    float vals[8];
    float m = -1e30f;
#pragma unroll
    for (int i = 0; i < 8; ++i) {
        vals[i] = row[tid + i * 256];
        m = fmaxf(m, vals[i]);
    }
#pragma unroll
    for (int off = 32; off >= 1; off >>= 1) m = fmaxf(m, __shfl_xor(m, off));
    __shared__ float redm[4];
    __shared__ float reds[4];
    if (lane == 0) redm[wave] = m;
    __syncthreads();
    m = fmaxf(fmaxf(redm[0], redm[1]), fmaxf(redm[2], redm[3]));

    float s = 0.f;
#pragma unroll
    for (int i = 0; i < 8; ++i) {
        vals[i] = __expf(vals[i] - m);
        s += vals[i];
    }
#pragma unroll
    for (int off = 32; off >= 1; off >>= 1) s += __shfl_xor(s, off);
    if (lane == 0) reds[wave] = s;
    __syncthreads();
    s = reds[0] + reds[1] + reds[2] + reds[3];
    float inv = 1.0f / s;
#pragma unroll
    for (int i = 0; i < 8; ++i) row[tid + i * 256] = vals[i] * inv;
}

extern "C" void kernel_launch(void* const* d_in, const int* in_sizes, int n_in,
                              void* d_out, int out_size, void* d_ws, size_t ws_size,
                              hipStream_t stream) {
    const float* stat = (const float*)d_in[0];   // [64,2048,256]
    const float* dyn  = (const float*)d_in[1];   // [64,2048,256]
    const float* dec  = (const float*)d_in[2];   // [64,256]
    const float* v    = (const float*)d_in[3];   // [1,768]
    const float* W    = (const float*)d_in[4];   // [768,768]
    float* out = (float*)d_out;                  // [64,2048]

    short* wpk  = (short*)d_ws;                                 // 786432 B
    float* bias = (float*)((char*)d_ws + (size_t)H3_ * K_ * 2); // 196608 B
    float* vsum = bias + B_ * H3_;                              // 4 B

    pack_w <<<(48 * 16 * 64 + 255) / 256, 256, 0, stream>>>(W, wpk);
    bias_k <<<193, 256, 0, stream>>>(W, dec, v, bias, vsum);
    score_k<<<(B_ * S_) / MT, 256, 0, stream>>>(stat, dyn, wpk, bias, v, vsum, out);
    softmax_k<<<B_, 256, 0, stream>>>(out);
}